// Round 1
// baseline (241.309 us; speedup 1.0000x reference)
//
#include <hip/hip_runtime.h>

// out[i] = g(data[i]) where g = (x*MAXVAL*ct) -> 3 Hermite-spline ODE steps -> (*st/MAXVAL).
// g is piecewise-smooth on [0,4] (post-ct space) and exactly affine outside.
// Strategy: pre-kernel tabulates g at 1024 knots over [-0.5, 4.5] into d_ws;
// main kernel does a fused lerp lookup from LDS. Memory-bound: 256 MiB HBM traffic.

#define MAXVAL_F 1.1752011936438014f

constexpr int   TAB_N  = 1024;
constexpr float TAB_L0 = -0.5f;
constexpr float TAB_H  = 5.0f / (float)TAB_N;   // covers [-0.5, 4.5]

// Exact reference-faithful evaluation of the 3-step map in post-ct space
// (excluding the final st/MAXVAL scale).
__device__ __forceinline__ float eval_exact(float x,
    const float* __restrict__ vt, const float* __restrict__ at) {
#pragma unroll
  for (int k = 0; k < 3; ++k) {
    float t = fminf(fmaxf(x, 0.0f), 4.0f);   // clip(x, 0, NUM_POINTS-1)
    int i0 = (int)t;                          // t >= 0 so trunc == floor
    if (i0 > 3) i0 = 3;                       // clip to NUM_POINTS-2
    float u  = t - (float)i0;
    float u2 = u * u, u3 = u2 * u;
    float h00 =  2.0f * u3 - 3.0f * u2 + 1.0f;
    float h10 =         u3 - 2.0f * u2 + u;
    float h01 = -2.0f * u3 + 3.0f * u2;
    float h11 =         u3 -        u2;
    // table layout: row 0 = values [0..4], row 1 = tangents [5..9]
    float vel = h00 * vt[i0] + h10 * vt[5 + i0] + h01 * vt[i0 + 1] + h11 * vt[6 + i0];
    float ang = h00 * at[i0] + h10 * at[5 + i0] + h01 * at[i0 + 1] + h11 * at[6 + i0];
    float sn = sinf(ang);
    float cs = cosf(ang);
    x = x + (vel * cs + x * vel * sn) * (1.0f / 3.0f);
  }
  return x;
}

// One tiny launch: 1024 threads, each computes g at its knot and the next knot
// (exactly), stores (g_j, g_{j+1}-g_j) for single-FMA lerp in the main kernel.
__global__ void build_table_kernel(const float* __restrict__ vt,
                                   const float* __restrict__ at,
                                   const float* __restrict__ stp,
                                   float2* __restrict__ gtab) {
  int j = blockIdx.x * blockDim.x + threadIdx.x;
  if (j >= TAB_N) return;
  float sc = stp[0] * (1.0f / MAXVAL_F);
  float x0 = TAB_L0 + TAB_H * (float)j;
  float x1 = TAB_L0 + TAB_H * (float)(j + 1);
  float g0 = eval_exact(x0, vt, at) * sc;
  float g1 = eval_exact(x1, vt, at) * sc;
  gtab[j] = make_float2(g0, g1 - g0);
}

// Main kernel: float4 streaming, per element one LDS float2 lookup + lerp.
// Index clamp WITHOUT clamping u -> linear extrapolation, exact in the affine tails.
__global__ __launch_bounds__(256) void apply_map_kernel(
    const float4* __restrict__ in, float4* __restrict__ out,
    const float2* __restrict__ gtab, const float* __restrict__ ctp, int nf4) {
  __shared__ float2 tab[TAB_N];
  {
    const float4* g4 = (const float4*)gtab;
    float4* t4 = (float4*)tab;
    for (int i = (int)threadIdx.x; i < TAB_N / 2; i += 256) t4[i] = g4[i];
  }
  // s = (data*MAXVAL*ct - L0)/h  folded into one FMA: s = data*C1 + C0
  float C1 = ctp[0] * (MAXVAL_F / TAB_H);
  const float C0 = -TAB_L0 / TAB_H;
  __syncthreads();

  int base = (int)blockIdx.x * 1024 + (int)threadIdx.x;
#pragma unroll
  for (int k = 0; k < 4; ++k) {
    int idx = base + k * 256;
    if (idx < nf4) {
      float4 d = in[idx];
      float v[4] = {d.x, d.y, d.z, d.w};
      float r[4];
#pragma unroll
      for (int c = 0; c < 4; ++c) {
        float s  = fmaf(v[c], C1, C0);
        float fj = floorf(s);
        fj = fminf(fmaxf(fj, 0.0f), (float)(TAB_N - 2));
        float u  = s - fj;                 // may be <0 or >1: extrapolation
        float2 e = tab[(int)fj];
        r[c] = fmaf(u, e.y, e.x);
      }
      float4 o; o.x = r[0]; o.y = r[1]; o.z = r[2]; o.w = r[3];
      out[idx] = o;
    }
  }
}

extern "C" void kernel_launch(void* const* d_in, const int* in_sizes, int n_in,
                              void* d_out, int out_size, void* d_ws, size_t ws_size,
                              hipStream_t stream) {
  const float* data = (const float*)d_in[0];
  const float* vel  = (const float*)d_in[1];
  const float* ang  = (const float*)d_in[2];
  const float* ct   = (const float*)d_in[3];
  const float* st   = (const float*)d_in[4];
  float*       outp = (float*)d_out;
  float2*      gtab = (float2*)d_ws;   // 1024 * 8 B = 8 KiB scratch

  // Build lookup table (rebuilt every call; d_ws is re-poisoned by harness).
  hipLaunchKernelGGL(build_table_kernel, dim3((TAB_N + 255) / 256), dim3(256), 0, stream,
                     vel, ang, st, gtab);

  int n   = in_sizes[0];          // 33,554,432 (divisible by 4)
  int nf4 = n / 4;
  int blocks = (nf4 + 1023) / 1024;   // 1024 float4 per block (16 elem/thread)
  hipLaunchKernelGGL(apply_map_kernel, dim3(blocks), dim3(256), 0, stream,
                     (const float4*)data, (float4*)outp, gtab, ct, nf4);
}